// Round 5
// baseline (795.671 us; speedup 1.0000x reference)
//
#include <hip/hip_runtime.h>
#include <math.h>

#define N_NODES 100000
#define N_EDGES 1600000
#define NGR 64
#define IMG_F 50176
#define NCLS 38
#define KSPLIT 196          // k-chunks of 256: 196*256 = 50176

typedef short bf16x8 __attribute__((ext_vector_type(8)));
typedef float f32x4 __attribute__((ext_vector_type(4)));
typedef unsigned int uint;

// fp32 pair -> packed bf16x2 (RNE)
__device__ __forceinline__ uint pk2(float a, float b) {
  uint ua = __float_as_uint(a), ub = __float_as_uint(b);
  ua = (ua + 0x7fffu + ((ua >> 16) & 1u)) >> 16;
  ub = (ub + 0x7fffu + ((ub >> 16) & 1u)) >> 16;
  return ua | (ub << 16);
}
__device__ __forceinline__ unsigned short f2bf(float x) {
  uint u = __float_as_uint(x);
  u = (u + 0x7fffu + ((u >> 16) & 1u)) >> 16;
  return (unsigned short)u;
}
__device__ __forceinline__ float bflo(uint u) { return __uint_as_float(u << 16); }
__device__ __forceinline__ float bfhi(uint u) { return __uint_as_float(u & 0xffff0000u); }

// ---------------- small helpers ----------------
__device__ __forceinline__ int lower_bound_i(const int* __restrict__ a, int n, int v) {
  int lo = 0, hi = n;
  while (lo < hi) { int mid = (lo + hi) >> 1; if (a[mid] < v) lo = mid + 1; else hi = mid; }
  return lo;
}

__global__ void k_deg(const int* __restrict__ dst, int* __restrict__ deg) {
  int e = blockIdx.x * 256 + threadIdx.x;
  if (e < N_EDGES) atomicAdd(&deg[dst[e]], 1);
}

// ---------------- block scan: rowptr = exclusive_scan(deg) ----------------
#define SCAN_CHUNK 512
#define SCAN_BLOCKS ((N_NODES + SCAN_CHUNK - 1) / SCAN_CHUNK)  // 196

__global__ __launch_bounds__(512)
void k_scan1(const int* __restrict__ deg, int* __restrict__ bsum) {
  __shared__ int s[512];
  int t = threadIdx.x;
  int i = blockIdx.x * SCAN_CHUNK + t;
  s[t] = (i < N_NODES) ? deg[i] : 0;
  __syncthreads();
  for (int off = 256; off > 0; off >>= 1) {
    if (t < off) s[t] += s[t + off];
    __syncthreads();
  }
  if (t == 0) bsum[blockIdx.x] = s[0];
}

__global__ __launch_bounds__(256)
void k_scan2(const int* __restrict__ bsum, int* __restrict__ boff) {
  __shared__ int s[256];
  int t = threadIdx.x;
  s[t] = (t < SCAN_BLOCKS) ? bsum[t] : 0;
  __syncthreads();
  for (int off = 1; off < 256; off <<= 1) {
    int v = (t >= off) ? s[t - off] : 0;
    __syncthreads();
    s[t] += v;
    __syncthreads();
  }
  if (t < SCAN_BLOCKS) boff[t] = (t == 0) ? 0 : s[t - 1];
}

// scan3 also produces dinv (reads deg anyway) — saves a launch
__global__ __launch_bounds__(512)
void k_scan3(const int* __restrict__ deg, const int* __restrict__ boff,
             int* __restrict__ rowptr, float* __restrict__ dinv) {
  __shared__ int s[512];
  int t = threadIdx.x;
  int i = blockIdx.x * SCAN_CHUNK + t;
  int d = (i < N_NODES) ? deg[i] : 0;
  s[t] = d;
  __syncthreads();
  for (int off = 1; off < 512; off <<= 1) {
    int v = (t >= off) ? s[t - off] : 0;
    __syncthreads();
    s[t] += v;
    __syncthreads();
  }
  if (i < N_NODES) {
    rowptr[i] = boff[blockIdx.x] + s[t] - d;
    dinv[i] = rsqrtf((float)d + 1.0f);
  }
  if (blockIdx.x == 0 && t == 0) rowptr[N_NODES] = N_EDGES;
}

__global__ void k_csr_fill(const int* __restrict__ src, const int* __restrict__ dst,
                           const int* __restrict__ rowptr, int* __restrict__ cur,
                           int* __restrict__ csr_src) {
  int e = blockIdx.x * 256 + threadIdx.x;
  if (e >= N_EDGES) return;
  int d = dst[e];
  int pos = rowptr[d] + atomicAdd(&cur[d], 1);
  csr_src[pos] = src[e];
}

// ---------------- GCN aggregation (gather, bf16, atomic-free) ----------------
// h holds h'[n] = h_lin[n]*dinv[n] (bf16). out[n] = bf16(dinv[n]*(h'[n]+sum h'[src])).
// 16 lanes/node; unroll-4 edge loop for 2x in-flight gather bytes (latency-bound).
template<int F, int VEC>
__global__ __launch_bounds__(256)
void k_agg_bf16(const unsigned short* __restrict__ h, const float* __restrict__ dinv,
                const int* __restrict__ rowptr, const int* __restrict__ csr_src,
                unsigned short* __restrict__ out) {
  constexpr int L = F / VEC;    // 16
  constexpr int NPB = 256 / L;  // 16
  constexpr int NU = VEC / 2;   // uints per lane
  int n = blockIdx.x * NPB + threadIdx.x / L;
  int lane = threadIdx.x % L;
  if (n >= N_NODES) return;
  const uint* hu = (const uint*)h;
  const int rs = F / 2;  // uints per feature row
  float acc[VEC];
  uint r0[NU];
  if constexpr (VEC == 8) *(uint4*)r0 = *(const uint4*)&hu[(size_t)n * rs + lane * NU];
  else                    *(uint2*)r0 = *(const uint2*)&hu[(size_t)n * rs + lane * NU];
#pragma unroll
  for (int j = 0; j < NU; j++) { acc[2*j] = bflo(r0[j]); acc[2*j+1] = bfhi(r0[j]); }
  int lo = rowptr[n], hi = rowptr[n + 1];
  int i = lo;
  for (; i + 4 <= hi; i += 4) {
    int s0 = csr_src[i], s1 = csr_src[i + 1], s2 = csr_src[i + 2], s3 = csr_src[i + 3];
    uint a0[NU], a1[NU], a2[NU], a3[NU];
    if constexpr (VEC == 8) {
      *(uint4*)a0 = *(const uint4*)&hu[(size_t)s0 * rs + lane * NU];
      *(uint4*)a1 = *(const uint4*)&hu[(size_t)s1 * rs + lane * NU];
      *(uint4*)a2 = *(const uint4*)&hu[(size_t)s2 * rs + lane * NU];
      *(uint4*)a3 = *(const uint4*)&hu[(size_t)s3 * rs + lane * NU];
    } else {
      *(uint2*)a0 = *(const uint2*)&hu[(size_t)s0 * rs + lane * NU];
      *(uint2*)a1 = *(const uint2*)&hu[(size_t)s1 * rs + lane * NU];
      *(uint2*)a2 = *(const uint2*)&hu[(size_t)s2 * rs + lane * NU];
      *(uint2*)a3 = *(const uint2*)&hu[(size_t)s3 * rs + lane * NU];
    }
#pragma unroll
    for (int j = 0; j < NU; j++) {
      acc[2*j]   += bflo(a0[j]) + bflo(a1[j]) + bflo(a2[j]) + bflo(a3[j]);
      acc[2*j+1] += bfhi(a0[j]) + bfhi(a1[j]) + bfhi(a2[j]) + bfhi(a3[j]);
    }
  }
  for (; i < hi; i++) {
    int s0 = csr_src[i];
    uint a0[NU];
    if constexpr (VEC == 8) *(uint4*)a0 = *(const uint4*)&hu[(size_t)s0 * rs + lane * NU];
    else                    *(uint2*)a0 = *(const uint2*)&hu[(size_t)s0 * rs + lane * NU];
#pragma unroll
    for (int j = 0; j < NU; j++) { acc[2*j] += bflo(a0[j]); acc[2*j+1] += bfhi(a0[j]); }
  }
  float dn = dinv[n];
  uint o[NU];
#pragma unroll
  for (int j = 0; j < NU; j++) o[j] = pk2(dn * acc[2*j], dn * acc[2*j+1]);
  uint* op = (uint*)out + (size_t)n * rs + lane * NU;
  if constexpr (VEC == 8) *(uint4*)op = *(uint4*)o;
  else                    *(uint2*)op = *(uint2*)o;
}

// ---------------- img GEMM: bf16 MFMA split-K (k-chunk 256), NO atomics ------
__global__ __launch_bounds__(256)
void k_img_mfma(const float* __restrict__ A, const float* __restrict__ B,
                float* __restrict__ partial) {
  __shared__ __align__(16) short Al[512 * 8];    // 8 KB
  __shared__ __align__(16) short Bl[1024 * 8];   // 16 KB
  const int tid = threadIdx.x;
  const int l = tid & 63, w = tid >> 6;
  const int col0 = blockIdx.x * 128;
  const int kbase = blockIdx.y * 256;
  const int kq_l = l >> 4, rr_l = l & 15;
  f32x4 acc[8];
#pragma unroll
  for (int ct = 0; ct < 8; ct++) acc[ct] = (f32x4)(0.f);

  for (int st = 0; st < 4; st++) {
    int k0 = kbase + st * 64;
    __syncthreads();
#pragma unroll
    for (int it = 0; it < 2; it++) {
      int c = tid + it * 256;
      int r = c >> 3, ko = c & 7;
      const float* ap = &A[(size_t)r * IMG_F + k0 + ko * 8];
      float4 f0 = *(const float4*)ap;
      float4 f1 = *(const float4*)(ap + 4);
      int kst = ko >> 2, kq = ko & 3, rt = r >> 4, rr = r & 15;
      int ci = ((kst * 4 + kq) * 4 + (rt ^ kq)) * 16 + rr;
      uint4 u = make_uint4(pk2(f0.x, f0.y), pk2(f0.z, f0.w),
                           pk2(f1.x, f1.y), pk2(f1.z, f1.w));
      *(uint4*)&Al[ci * 8] = u;
    }
    {
      int col4 = tid & 31, ko = tid >> 5;
      const float* bp = &B[(size_t)(k0 + ko * 8) * 1024 + col0 + col4 * 4];
      float fb[8][4];
#pragma unroll
      for (int i2 = 0; i2 < 8; i2++)
        *(float4*)&fb[i2][0] = *(const float4*)(bp + (size_t)i2 * 1024);
      int kst = ko >> 2, kq = ko & 3;
#pragma unroll
      for (int c2 = 0; c2 < 4; c2++) {
        int col = col4 * 4 + c2;
        int ct = col >> 4, colin = col & 15;
        int ci = ((kst * 4 + kq) * 8 + (ct ^ kq)) * 16 + colin;
        uint4 u = make_uint4(pk2(fb[0][c2], fb[1][c2]), pk2(fb[2][c2], fb[3][c2]),
                             pk2(fb[4][c2], fb[5][c2]), pk2(fb[6][c2], fb[7][c2]));
        *(uint4*)&Bl[ci * 8] = u;
      }
    }
    __syncthreads();
#pragma unroll
    for (int kst = 0; kst < 2; kst++) {
      bf16x8 af = *(bf16x8*)&Al[(((kst * 4 + kq_l) * 4 + (w ^ kq_l)) * 16 + rr_l) * 8];
#pragma unroll
      for (int ct = 0; ct < 8; ct++) {
        bf16x8 bf = *(bf16x8*)&Bl[(((kst * 4 + kq_l) * 8 + (ct ^ kq_l)) * 16 + rr_l) * 8];
        acc[ct] = __builtin_amdgcn_mfma_f32_16x16x32_bf16(af, bf, acc[ct], 0, 0, 0);
      }
    }
  }
  float* P = partial + (size_t)blockIdx.y * 64 * 1024;
#pragma unroll
  for (int ct = 0; ct < 8; ct++)
#pragma unroll
    for (int rg = 0; rg < 4; rg++) {
      int row = w * 16 + (l >> 4) * 4 + rg;
      int col = col0 + ct * 16 + (l & 15);
      P[row * 1024 + col] = acc[ct][rg];
    }
}

// fused: tmp1_row = bm0 + sum_ks partial[ks][r][:]; x0[r] = tmp1_row @ Wm1 + bm1
__global__ __launch_bounds__(256)
void k_img_tail(const float* __restrict__ partial, const float* __restrict__ bm0,
                const float* __restrict__ Wm1, const float* __restrict__ bm1,
                float* __restrict__ x0) {
  __shared__ float tmp_l[1024];
  __shared__ float red[4][64];
  const int r = blockIdx.x;
  const int t = threadIdx.x;
#pragma unroll
  for (int j = 0; j < 4; j++) {
    int k = t + j * 256;
    float s = bm0[k];
    const float* p = partial + (size_t)r * 1024 + k;
    for (int ks = 0; ks < KSPLIT; ks++) s += p[(size_t)ks * 65536];
    tmp_l[k] = s;
  }
  __syncthreads();
  const int c = t & 63, q = t >> 6;
  float acc = 0.f;
  for (int k = q * 256; k < (q + 1) * 256; k++)
    acc = fmaf(tmp_l[k], Wm1[k * 64 + c], acc);
  red[q][c] = acc;
  __syncthreads();
  if (q == 0) x0[r * 64 + c] = red[0][c] + red[1][c] + red[2][c] + red[3][c] + bm1[c];
}

// ---------------- node GEMM: C[M,N] = dinv[row]*(act(A[M,128]) @ W[128,N]), bf16
template<int N, bool RELU_BIAS, bool BF16_IN>
__global__ __launch_bounds__(256)
void k_gcn_mfma(const void* __restrict__ Ain, const float* __restrict__ W,
                const float* __restrict__ abias, const float* __restrict__ dinv,
                unsigned short* __restrict__ C, int M) {
  constexpr int NT16 = N / 16;
  __shared__ __align__(16) short Al[1024 * 8];
  __shared__ __align__(16) short Wl[256 * NT16 * 8];
  const int tid = threadIdx.x;
  const int l = tid & 63, w = tid >> 6;
  const int row0 = blockIdx.x * 64;
  const int kq_l = l >> 4, rr_l = l & 15;

#pragma unroll
  for (int it = 0; it < 4; it++) {
    int c = tid + it * 256;
    int r = c >> 4, ko = c & 15;
    int row = row0 + r;
    float f[8] = {0.f, 0.f, 0.f, 0.f, 0.f, 0.f, 0.f, 0.f};
    if (row < M) {
      if constexpr (BF16_IN) {
        const uint* ap = (const uint*)Ain + (size_t)row * 64 + ko * 4;
        uint4 u = *(const uint4*)ap;
        f[0] = bflo(u.x); f[1] = bfhi(u.x); f[2] = bflo(u.y); f[3] = bfhi(u.y);
        f[4] = bflo(u.z); f[5] = bfhi(u.z); f[6] = bflo(u.w); f[7] = bfhi(u.w);
      } else {
        const float* ap = (const float*)Ain + (size_t)row * 128 + ko * 8;
        *(float4*)&f[0] = *(const float4*)ap;
        *(float4*)&f[4] = *(const float4*)(ap + 4);
      }
      if (RELU_BIAS) {
        const float* bp = &abias[ko * 8];
#pragma unroll
        for (int j = 0; j < 8; j++) f[j] = fmaxf(f[j] + bp[j], 0.f);
      }
    }
    int kst = ko >> 2, kq = ko & 3, rt = r >> 4, rr = r & 15;
    int ci = ((kst * 4 + kq) * 4 + (rt ^ kq)) * 16 + rr;
    uint4 u = make_uint4(pk2(f[0], f[1]), pk2(f[2], f[3]),
                         pk2(f[4], f[5]), pk2(f[6], f[7]));
    *(uint4*)&Al[ci * 8] = u;
  }
#pragma unroll
  for (int it = 0; it < (N == 128 ? 2 : 1); it++) {
    int mt = tid + it * 256;
    int col4 = mt % (N / 4), ko = mt / (N / 4);
    float fb[8][4];
#pragma unroll
    for (int i2 = 0; i2 < 8; i2++)
      *(float4*)&fb[i2][0] = *(const float4*)&W[(size_t)(ko * 8 + i2) * N + col4 * 4];
    int kst = ko >> 2, kq = ko & 3;
#pragma unroll
    for (int c2 = 0; c2 < 4; c2++) {
      int col = col4 * 4 + c2;
      int ct = col >> 4, colin = col & 15;
      int ci = ((kst * 4 + kq) * NT16 + (ct ^ kq)) * 16 + colin;
      uint4 u = make_uint4(pk2(fb[0][c2], fb[1][c2]), pk2(fb[2][c2], fb[3][c2]),
                           pk2(fb[4][c2], fb[5][c2]), pk2(fb[6][c2], fb[7][c2]));
      *(uint4*)&Wl[ci * 8] = u;
    }
  }
  __syncthreads();

  f32x4 acc[NT16];
#pragma unroll
  for (int ct = 0; ct < NT16; ct++) acc[ct] = (f32x4)(0.f);
#pragma unroll
  for (int kst = 0; kst < 4; kst++) {
    bf16x8 af = *(bf16x8*)&Al[(((kst * 4 + kq_l) * 4 + (w ^ kq_l)) * 16 + rr_l) * 8];
#pragma unroll
    for (int ct = 0; ct < NT16; ct++) {
      bf16x8 bf = *(bf16x8*)&Wl[(((kst * 4 + kq_l) * NT16 + (ct ^ kq_l)) * 16 + rr_l) * 8];
      acc[ct] = __builtin_amdgcn_mfma_f32_16x16x32_bf16(af, bf, acc[ct], 0, 0, 0);
    }
  }
#pragma unroll
  for (int rg = 0; rg < 4; rg++) {
    int row = row0 + w * 16 + (l >> 4) * 4 + rg;
    if (row < M) {
      float dsc = dinv[row];
#pragma unroll
      for (int ct = 0; ct < NT16; ct++)
        C[(size_t)row * N + ct * 16 + (l & 15)] = f2bf(acc[ct][rg] * dsc);
    }
  }
}

// ---------------- pool (bf16 input, + bias + relu) ----------------
__global__ __launch_bounds__(256)
void k_pool(const unsigned short* __restrict__ h2, const float* __restrict__ b2,
            const int* __restrict__ batch, float* __restrict__ g) {
  int b = blockIdx.x;
  int f = threadIdx.x & 63;
  int q = threadIdx.x >> 6;
  int lo = lower_bound_i(batch, N_NODES, b);
  int hi = lower_bound_i(batch, N_NODES, b + 1);
  float bias = b2[f];
  float acc = 0.f;
  for (int i = lo + q; i < hi; i += 4)
    acc += fmaxf(__uint_as_float((uint)h2[(size_t)i * 64 + f] << 16) + bias, 0.f);
  __shared__ float red[4][64];
  red[q][f] = acc;
  __syncthreads();
  if (q == 0) g[b * 64 + f] = red[0][f] + red[1][f] + red[2][f] + red[3][f];
}

// ---------------- head ----------------
__global__ __launch_bounds__(64)
void k_final(const float* __restrict__ x0, const float* __restrict__ g,
             const float* __restrict__ Wmx, const float* __restrict__ bmx,
             const float* __restrict__ Wfc, const float* __restrict__ bfc,
             float* __restrict__ out) {
  int r = blockIdx.x;
  int c = threadIdx.x;
  __shared__ float sx[128];
  __shared__ float slog[NCLS];
  __shared__ float sred;
  float acc = bmx[c];
#pragma unroll 8
  for (int k = 0; k < 64; k++) acc = fmaf(g[r * 64 + k], Wmx[k * 64 + c], acc);
  sx[64 + c] = acc;
  sx[c] = x0[r * 64 + c];
  __syncthreads();
  float lg = 0.f;
  if (c < NCLS) {
    lg = bfc[c];
#pragma unroll 8
    for (int k = 0; k < 128; k++) lg = fmaf(sx[k], Wfc[k * NCLS + c], lg);
    slog[c] = lg;
  }
  __syncthreads();
  if (c == 0) {
    float m = -1e30f;
    for (int j = 0; j < NCLS; j++) m = fmaxf(m, slog[j]);
    float s = 0.f;
    for (int j = 0; j < NCLS; j++) s += expf(slog[j] - m);
    sred = m + logf(s);
  }
  __syncthreads();
  if (c < NCLS) out[r * NCLS + c] = lg - sred;
}

// ---------------- launch ----------------
extern "C" void kernel_launch(void* const* d_in, const int* in_sizes, int n_in,
                              void* d_out, int out_size, void* d_ws, size_t ws_size,
                              hipStream_t stream) {
  const float* x    = (const float*)d_in[0];
  const int*   edge = (const int*)d_in[1];
  const float* img  = (const float*)d_in[2];
  const int*   batch= (const int*)d_in[3];
  const float* W1   = (const float*)d_in[4];
  const float* b1   = (const float*)d_in[5];
  const float* W2   = (const float*)d_in[6];
  const float* b2   = (const float*)d_in[7];
  const float* Wm0  = (const float*)d_in[8];
  const float* bm0  = (const float*)d_in[9];
  const float* Wm1  = (const float*)d_in[10];
  const float* bm1  = (const float*)d_in[11];
  const float* Wmx  = (const float*)d_in[12];
  const float* bmx  = (const float*)d_in[13];
  const float* Wfc  = (const float*)d_in[14];
  const float* bfc  = (const float*)d_in[15];
  float* out = (float*)d_out;
  const int* srcp = edge;
  const int* dstp = edge + N_EDGES;

  char* ws = (char*)d_ws;
  size_t off = 0;
  auto alloc = [&](size_t bytes) {
    void* p = ws + off;
    off += (bytes + 255) & ~(size_t)255;
    return p;
  };
  int*   deg    = (int*)  alloc((size_t)N_NODES * 4);   // reused as csr cursor
  float* dinv   = (float*)alloc((size_t)N_NODES * 4);
  int*   rowptr = (int*)  alloc((size_t)(N_NODES + 1) * 4);
  int*   bsum   = (int*)  alloc((size_t)SCAN_BLOCKS * 4);
  int*   boff   = (int*)  alloc((size_t)SCAN_BLOCKS * 4);
  int*   csr    = (int*)  alloc((size_t)N_EDGES * 4);
  unsigned short* bufA = (unsigned short*)alloc((size_t)N_NODES * 128 * 2);
  unsigned short* bufB = (unsigned short*)alloc((size_t)N_NODES * 128 * 2);
  float* partial = (float*)alloc((size_t)KSPLIT * 65536 * 4);  // 51.4 MB
  float* x0     = (float*)alloc(64 * 64 * 4);
  float* g      = (float*)alloc(64 * 64 * 4);
  (void)ws_size; (void)in_sizes; (void)n_in; (void)out_size;

  // CSR build: deg -> (rowptr, dinv) -> fill (deg reused as cursor)
  hipMemsetAsync(deg, 0, (size_t)N_NODES * 4, stream);
  k_deg  <<<(N_EDGES + 255) / 256, 256, 0, stream>>>(dstp, deg);
  k_scan1<<<SCAN_BLOCKS, 512, 0, stream>>>(deg, bsum);
  k_scan2<<<1, 256, 0, stream>>>(bsum, boff);
  k_scan3<<<SCAN_BLOCKS, 512, 0, stream>>>(deg, boff, rowptr, dinv);
  hipMemsetAsync(deg, 0, (size_t)N_NODES * 4, stream);
  k_csr_fill<<<(N_EDGES + 255) / 256, 256, 0, stream>>>(srcp, dstp, rowptr, deg, csr);

  // image branch (bf16 MFMA split-K 196 chunks; fused reduce+gemm2 tail)
  k_img_mfma<<<dim3(8, KSPLIT), 256, 0, stream>>>(img, Wm0, partial);
  k_img_tail<<<64, 256, 0, stream>>>(partial, bm0, Wm1, bm1, x0);

  // GCN layer 1: h1' = dinv*(x @ W1) in bf16 ; gather-agg
  k_gcn_mfma<128, false, false><<<(N_NODES + 63) / 64, 256, 0, stream>>>(
      x, W1, nullptr, dinv, bufA, N_NODES);
  k_agg_bf16<128, 8><<<(N_NODES + 15) / 16, 256, 0, stream>>>(
      bufA, dinv, rowptr, csr, bufB);

  // GCN layer 2: h2' = dinv*(relu(agg1 + b1) @ W2) in bf16 ; gather-agg
  k_gcn_mfma<64, true, true><<<(N_NODES + 63) / 64, 256, 0, stream>>>(
      bufB, W2, b1, dinv, bufA, N_NODES);
  k_agg_bf16<64, 4><<<(N_NODES + 15) / 16, 256, 0, stream>>>(
      bufA, dinv, rowptr, csr, bufB);

  // pool + head
  k_pool <<<NGR, 256, 0, stream>>>(bufB, b2, batch, g);
  k_final<<<NGR, 64, 0, stream>>>(x0, g, Wmx, bmx, Wfc, bfc, out);
}